// Round 1
// baseline (45.079 us; speedup 1.0000x reference)
//
#include <hip/hip_runtime.h>

// out[row, w] = prod_{w'<=w} cos(x[row, w']),  row = (b,t,h), w in [0,64)
// 16 lanes per row, 4 wires per lane (float4), shfl-based product scan.

__global__ __launch_bounds__(256) void quantum_cumprod_cos_kernel(
    const float4* __restrict__ x, float4* __restrict__ out, int nchunks) {
    const int tid    = blockIdx.x * blockDim.x + threadIdx.x;
    const int stride = gridDim.x * blockDim.x;  // multiple of 16

    for (int i = tid; i < nchunks; i += stride) {
        const int sub = i & 15;  // position of this 4-wire chunk within its row
                                 // == (lane & 15) since stride % 16 == 0

        const float4 v = x[i];
        // cos of the 4 wires in this chunk
        const float c0 = __cosf(v.x);
        const float c1 = __cosf(v.y);
        const float c2 = __cosf(v.z);
        const float c3 = __cosf(v.w);
        // local inclusive prefix products
        const float p0 = c0;
        const float p1 = p0 * c1;
        const float p2 = p1 * c2;
        const float p3 = p2 * c3;

        // exclusive product-scan of p3 across the 16-lane group:
        // e = prod of p3 over lanes with lower sub (1.0 for sub==0)
        float e = __shfl_up(p3, 1, 16);
        if (sub == 0) e = 1.0f;
#pragma unroll
        for (int d = 1; d < 16; d <<= 1) {
            const float t = __shfl_up(e, d, 16);
            if (sub >= d) e *= t;
        }

        float4 o;
        o.x = e * p0;
        o.y = e * p1;
        o.z = e * p2;
        o.w = e * p3;
        out[i] = o;
    }
}

extern "C" void kernel_launch(void* const* d_in, const int* in_sizes, int n_in,
                              void* d_out, int out_size, void* d_ws, size_t ws_size,
                              hipStream_t stream) {
    (void)d_ws; (void)ws_size; (void)n_in;
    const float4* x = (const float4*)d_in[0];  // (8,4096,1024) fp32
    // d_in[1] (circuit_params) drops out analytically — unused.
    float4* out = (float4*)d_out;              // (8,4096,1024) fp32

    const int nchunks = out_size / 4;          // 8*4096*1024/4 = 8,388,608
    const int threads = 256;
    int blocks = (nchunks + threads - 1) / threads;
    if (blocks > 2048) blocks = 2048;          // 8 blocks/CU, grid-stride the rest

    quantum_cumprod_cos_kernel<<<blocks, threads, 0, stream>>>(x, out, nchunks);
}